// Round 1
// baseline (1824.452 us; speedup 1.0000x reference)
//
#include <hip/hip_runtime.h>

typedef __bf16 bf16;
typedef float f32x4 __attribute__((ext_vector_type(4)));
typedef bf16 bf16x8 __attribute__((ext_vector_type(8)));
typedef bf16 bf16x4 __attribute__((ext_vector_type(4)));

constexpr int Bc = 4, Sc = 2048, Dc = 1024, Hc = 16, DKc = 64;
constexpr float NEGc = -10000.0f;

// ---------------------------------------------------------------------------
// Kernel 1: QKV projection GEMM.  y = x @ W^T + b, x:[8192,1024] W:[1024,1024]
// both K-contiguous (B^T pattern).  Output bf16 head-major [B,H,S,64].
// 128x128 tile, BK=32, 4 waves in 2x2, 16 MFMA 16x16x32 per wave per K-iter.
// ---------------------------------------------------------------------------
__global__ __launch_bounds__(256, 2) void proj_kernel(
    const float* __restrict__ xq, const float* __restrict__ xk, const float* __restrict__ xv,
    const float* __restrict__ Wq, const float* __restrict__ bq,
    const float* __restrict__ Wk, const float* __restrict__ bk,
    const float* __restrict__ Wv, const float* __restrict__ bv,
    bf16* __restrict__ qh, bf16* __restrict__ kh, bf16* __restrict__ vh)
{
    const int z = blockIdx.z;
    const float* x    = (z == 0) ? xq : (z == 1) ? xk : xv;
    const float* W    = (z == 0) ? Wq : (z == 1) ? Wk : Wv;
    const float* bias = (z == 0) ? bq : (z == 1) ? bk : bv;
    bf16* dst         = (z == 0) ? qh : (z == 1) ? kh : vh;

    const int tid = threadIdx.x;
    const int wave = tid >> 6, lane = tid & 63, quad = lane >> 4, m16 = lane & 15;
    const int wm = (wave >> 1) * 64, wn = (wave & 1) * 64;
    const int m0 = blockIdx.y * 128, n0 = blockIdx.x * 128;

    // stride 40 bf16 = 20 words: quad lanes land 2-way per bank (free, m136)
    __shared__ bf16 As[128][40];
    __shared__ bf16 Bs[128][40];

    const f32x4 zero4 = {0.f, 0.f, 0.f, 0.f};
    f32x4 acc[4][4];
#pragma unroll
    for (int i = 0; i < 4; i++)
#pragma unroll
        for (int j = 0; j < 4; j++) acc[i][j] = zero4;

    for (int kk = 0; kk < 32; ++kk) {
        const int k0 = kk * 32;
#pragma unroll
        for (int i = 0; i < 4; i++) {
            int f4 = tid + i * 256;            // 0..1023 float4 slots (128 rows x 8)
            int r = f4 >> 3, c4 = (f4 & 7) * 4;
            float4 a = *(const float4*)&x[(size_t)(m0 + r) * Dc + k0 + c4];
            float4 w = *(const float4*)&W[(size_t)(n0 + r) * Dc + k0 + c4];
            bf16x4 av; av.x = (bf16)a.x; av.y = (bf16)a.y; av.z = (bf16)a.z; av.w = (bf16)a.w;
            bf16x4 wv; wv.x = (bf16)w.x; wv.y = (bf16)w.y; wv.z = (bf16)w.z; wv.w = (bf16)w.w;
            *(bf16x4*)&As[r][c4] = av;
            *(bf16x4*)&Bs[r][c4] = wv;
        }
        __syncthreads();
        bf16x8 af[4], bfr[4];
#pragma unroll
        for (int t = 0; t < 4; t++) {
            af[t]  = *(const bf16x8*)&As[wm + t * 16 + m16][quad * 8];
            bfr[t] = *(const bf16x8*)&Bs[wn + t * 16 + m16][quad * 8];
        }
#pragma unroll
        for (int mt = 0; mt < 4; mt++)
#pragma unroll
            for (int nt = 0; nt < 4; nt++)
                acc[mt][nt] = __builtin_amdgcn_mfma_f32_16x16x32_bf16(af[mt], bfr[nt], acc[mt][nt], 0, 0, 0);
        __syncthreads();
    }

    // epilogue: +bias, scatter bf16 to [B,H,S,64]
#pragma unroll
    for (int nt = 0; nt < 4; nt++) {
        int n = n0 + wn + nt * 16 + m16;
        float bval = bias[n];
        int h = n >> 6, d = n & 63;
#pragma unroll
        for (int mt = 0; mt < 4; mt++) {
#pragma unroll
            for (int r = 0; r < 4; r++) {
                int m = m0 + wm + mt * 16 + quad * 4 + r;
                int bb = m >> 11, s = m & 2047;     // S = 2048
                float val = acc[mt][nt][r] + bval;
                dst[(((size_t)(bb * Hc + h)) * Sc + s) * DKc + d] = (bf16)val;
            }
        }
    }
}

// ---------------------------------------------------------------------------
// Kernel 2: transpose V  [B,H,S,64] -> [B,H,64,S]  (so PV B-frags are 16B loads)
// ---------------------------------------------------------------------------
__global__ __launch_bounds__(256) void vtrans_kernel(const bf16* __restrict__ vh,
                                                     bf16* __restrict__ vt)
{
    const int tid = threadIdx.x;
    const int bh = blockIdx.y, s0 = blockIdx.x * 64;
    __shared__ bf16 tile[64][72];   // 144 B rows (16B multiple), banks spread
    const bf16* src = vh + ((size_t)bh * Sc + s0) * DKc;
#pragma unroll
    for (int i = 0; i < 2; i++) {
        int v = tid + i * 256;           // 0..511 vec8 units
        int sl = v >> 3, d8 = (v & 7) * 8;
        *(bf16x8*)&tile[sl][d8] = *(const bf16x8*)&src[sl * DKc + d8];
    }
    __syncthreads();
#pragma unroll
    for (int i = 0; i < 2; i++) {
        int v = tid + i * 256;
        int d = v >> 3, s8 = (v & 7) * 8;
        bf16x8 o;
#pragma unroll
        for (int j = 0; j < 8; j++) o[j] = tile[s8 + j][d];
        *(bf16x8*)&vt[((size_t)bh * DKc + d) * Sc + s0 + s8] = o;
    }
}

// ---------------------------------------------------------------------------
// Kernel 3: attention.  One block = (b, h, 16 q-rows).  Full 2048-key score row
// kept in registers (32 x f32x4 per lane, C-frag layout).  Softmax in fp32 in
// registers; normalized probs -> d_out (fp32) and LDS (bf16, XOR-8 swizzled)
// for the PV MFMA pass.
// ---------------------------------------------------------------------------
__global__ __launch_bounds__(256, 2) void attn_kernel(
    const bf16* __restrict__ qh, const bf16* __restrict__ kh, const bf16* __restrict__ vt,
    const int* __restrict__ mask, float* __restrict__ attn_out, float* __restrict__ out)
{
    const int qt = blockIdx.x, h = blockIdx.y, b = blockIdx.z;
    const int bh = b * Hc + h, q0 = qt * 16;
    const int tid = threadIdx.x;
    const int wave = tid >> 6, lane = tid & 63, quad = lane >> 4, m16 = lane & 15;

    __shared__ bf16 sc[16][2048];               // exactly 64 KB; holds probs (bf16)
    float* red = reinterpret_cast<float*>(&sc[0][0]);  // reduction scratch (before probs)

    const bf16* qrow = qh + ((size_t)bh * Sc + q0) * DKc;
    const bf16* krow = kh + (size_t)bh * Sc * DKc;
    const bf16* vrow = vt + (size_t)bh * DKc * Sc;

    // Q fragments (rows q0..q0+15), K split 0..31 / 32..63
    const bf16x8 aq0 = *(const bf16x8*)&qrow[m16 * DKc + quad * 8];
    const bf16x8 aq1 = *(const bf16x8*)&qrow[m16 * DKc + 32 + quad * 8];

    const f32x4 zero4 = {0.f, 0.f, 0.f, 0.f};
    f32x4 acc[32];
#pragma unroll
    for (int t = 0; t < 32; t++) acc[t] = zero4;

    // ---- QK^T: wave w handles key tiles t*4+w ----
#pragma unroll
    for (int t = 0; t < 32; t++) {
        const int n0 = (t * 4 + wave) * 16;
        const bf16* kb = &krow[(size_t)(n0 + m16) * DKc + quad * 8];
        bf16x8 b0 = *(const bf16x8*)kb;
        bf16x8 b1 = *(const bf16x8*)(kb + 32);
        acc[t] = __builtin_amdgcn_mfma_f32_16x16x32_bf16(aq0, b0, acc[t], 0, 0, 0);
        acc[t] = __builtin_amdgcn_mfma_f32_16x16x32_bf16(aq1, b1, acc[t], 0, 0, 0);
    }

    // ---- scale + mask adders + running max (all fp32 in registers) ----
    float rmax[4] = {-3e38f, -3e38f, -3e38f, -3e38f};
#pragma unroll
    for (int t = 0; t < 32; t++) {
        const int kcol = (t * 4 + wave) * 16 + m16;
#pragma unroll
        for (int r = 0; r < 4; r++) {
            const int grow = q0 + quad * 4 + r;
            const int mv = mask[((size_t)b * Sc + grow) * Sc + kcol];
            float s = acc[t][r] * 0.125f;
            s += (mv == 0) ? NEGc : 0.f;        // padding mask adder
            s += (kcol > grow) ? NEGc : 0.f;    // causal adder
            acc[t][r] = s;
            rmax[r] = fmaxf(rmax[r], s);
        }
    }
    // reduce across the 16 lanes of each quad (rows live per-quad)
#pragma unroll
    for (int off = 1; off < 16; off <<= 1)
#pragma unroll
        for (int r = 0; r < 4; r++) rmax[r] = fmaxf(rmax[r], __shfl_xor(rmax[r], off, 64));
    if (m16 == 0) {
#pragma unroll
        for (int r = 0; r < 4; r++) red[wave * 16 + quad * 4 + r] = rmax[r];
    }
    __syncthreads();
#pragma unroll
    for (int r = 0; r < 4; r++) {
        const int row = quad * 4 + r;
        rmax[r] = fmaxf(fmaxf(red[row], red[16 + row]), fmaxf(red[32 + row], red[48 + row]));
    }

    // ---- exp + sum ----
    float rsum[4] = {0.f, 0.f, 0.f, 0.f};
#pragma unroll
    for (int t = 0; t < 32; t++)
#pragma unroll
        for (int r = 0; r < 4; r++) {
            float e = __expf(acc[t][r] - rmax[r]);
            acc[t][r] = e;
            rsum[r] += e;
        }
#pragma unroll
    for (int off = 1; off < 16; off <<= 1)
#pragma unroll
        for (int r = 0; r < 4; r++) rsum[r] += __shfl_xor(rsum[r], off, 64);
    if (m16 == 0) {
#pragma unroll
        for (int r = 0; r < 4; r++) red[64 + wave * 16 + quad * 4 + r] = rsum[r];
    }
    __syncthreads();
    float inv[4];
#pragma unroll
    for (int r = 0; r < 4; r++) {
        const int row = quad * 4 + r;
        inv[r] = 1.0f / (red[64 + row] + red[80 + row] + red[96 + row] + red[112 + row]);
    }
    __syncthreads();   // all reads of `red` done before probs clobber sc

    // ---- write normalized probs: fp32 -> global attn, bf16 -> LDS (swizzled) ----
    float* arow_base = attn_out + ((size_t)bh * Sc + q0) * Sc;
#pragma unroll
    for (int t = 0; t < 32; t++) {
        const int kcol = (t * 4 + wave) * 16 + m16;
#pragma unroll
        for (int r = 0; r < 4; r++) {
            const int row = quad * 4 + r;
            const float p = acc[t][r] * inv[r];
            arow_base[(size_t)row * Sc + kcol] = p;
            sc[row][kcol ^ ((row & 7) << 3)] = (bf16)p;
        }
    }
    __syncthreads();

    // ---- PV: wave w computes d-cols w*16..w*16+15; A from LDS, B from v^T ----
    const int dcol = wave * 16 + m16;
    const bf16* vbase = &vrow[(size_t)dcol * Sc];
    f32x4 oacc = zero4;
#pragma unroll 8
    for (int ks = 0; ks < 64; ks++) {
        const int k0 = ks * 32 + quad * 8;
        bf16x8 a  = *(const bf16x8*)&sc[m16][k0 ^ ((m16 & 7) << 3)];
        bf16x8 bv8 = *(const bf16x8*)&vbase[k0];
        oacc = __builtin_amdgcn_mfma_f32_16x16x32_bf16(a, bv8, oacc, 0, 0, 0);
    }
    float* obase = out + ((size_t)(b * Sc + q0)) * Dc + h * DKc;
#pragma unroll
    for (int r = 0; r < 4; r++) {
        const int row = quad * 4 + r;
        obase[(size_t)row * Dc + dcol] = oacc[r];
    }
}

// ---------------------------------------------------------------------------
// Kernel 4: residual add + LayerNorm, in place on d_out's `out` region.
// ---------------------------------------------------------------------------
__global__ __launch_bounds__(256) void ln_kernel(float* __restrict__ out,
                                                 const float* __restrict__ resid,
                                                 const float* __restrict__ gw,
                                                 const float* __restrict__ bw)
{
    const int row = blockIdx.x, tid = threadIdx.x;
    float* orow = out + (size_t)row * Dc;
    const float* rrow = resid + (size_t)row * Dc;
    float4 x = *(const float4*)&orow[tid * 4];
    float4 rr = *(const float4*)&rrow[tid * 4];
    x.x += rr.x; x.y += rr.y; x.z += rr.z; x.w += rr.w;
    float s1 = x.x + x.y + x.z + x.w;
    float s2 = x.x * x.x + x.y * x.y + x.z * x.z + x.w * x.w;
#pragma unroll
    for (int off = 1; off < 64; off <<= 1) {
        s1 += __shfl_xor(s1, off, 64);
        s2 += __shfl_xor(s2, off, 64);
    }
    __shared__ float red[8];
    const int wave = tid >> 6, lane = tid & 63;
    if (lane == 0) { red[wave] = s1; red[4 + wave] = s2; }
    __syncthreads();
    s1 = red[0] + red[1] + red[2] + red[3];
    s2 = red[4] + red[5] + red[6] + red[7];
    const float mu = s1 * (1.f / Dc);
    const float var = s2 * (1.f / Dc) - mu * mu;
    const float rstd = rsqrtf(var + 1e-5f);
    float4 g4 = *(const float4*)&gw[tid * 4];
    float4 b4 = *(const float4*)&bw[tid * 4];
    float4 y;
    y.x = (x.x - mu) * rstd * g4.x + b4.x;
    y.y = (x.y - mu) * rstd * g4.y + b4.y;
    y.z = (x.z - mu) * rstd * g4.z + b4.z;
    y.w = (x.w - mu) * rstd * g4.w + b4.w;
    *(float4*)&orow[tid * 4] = y;
}

// ---------------------------------------------------------------------------
extern "C" void kernel_launch(void* const* d_in, const int* in_sizes, int n_in,
                              void* d_out, int out_size, void* d_ws, size_t ws_size,
                              hipStream_t stream)
{
    (void)in_sizes; (void)n_in; (void)out_size; (void)ws_size;
    const float* q    = (const float*)d_in[0];
    const float* k    = (const float*)d_in[1];
    const float* v    = (const float*)d_in[2];
    const int*   mask = (const int*)d_in[3];
    const float* Wq   = (const float*)d_in[4];
    const float* bq   = (const float*)d_in[5];
    const float* Wk   = (const float*)d_in[6];
    const float* bk   = (const float*)d_in[7];
    const float* Wv   = (const float*)d_in[8];
    const float* bv   = (const float*)d_in[9];
    const float* g    = (const float*)d_in[10];
    const float* bet  = (const float*)d_in[11];

    float* out  = (float*)d_out;                     // [B,S,D]
    float* attn = out + (size_t)Bc * Sc * Dc;        // [B,H,S,S]

    const size_t headN = (size_t)Bc * Hc * Sc * DKc; // 8.39M bf16 = 16 MB
    bf16* qh = (bf16*)d_ws;
    bf16* kh = qh + headN;
    bf16* vh = kh + headN;
    bf16* vt = vh + headN;

    proj_kernel<<<dim3(8, 64, 3), 256, 0, stream>>>(q, k, v, Wq, bq, Wk, bk, Wv, bv, qh, kh, vh);
    vtrans_kernel<<<dim3(Sc / 64, Bc * Hc), 256, 0, stream>>>(vh, vt);
    attn_kernel<<<dim3(Sc / 16, Hc, Bc), 256, 0, stream>>>(qh, kh, vt, mask, attn, out);
    ln_kernel<<<dim3(Bc * Sc), 256, 0, stream>>>(out, q, g, bet);
}